// Round 3
// baseline (358.922 us; speedup 1.0000x reference)
//
#include <hip/hip_runtime.h>

// B=8, T=8, S=500, F_IN=32, F=F_OUT=64, K=3, L=3
#define BB 8
#define TT 8
#define SS 500
#define FIN 32
#define FF 64
#define NROWS (BB * TT * SS)   // 32000
#define TS_STRIDE (SS * FF)    // 32000 floats between t slices
#define KP 512                 // padded K for bf16 operands

typedef short bf16x8 __attribute__((ext_vector_type(8)));
typedef float floatx4 __attribute__((ext_vector_type(4)));

__device__ __forceinline__ unsigned f2bf(float x) {
    unsigned u = __builtin_bit_cast(unsigned, x);
    return (u + 0x7FFFu + ((u >> 16) & 1u)) >> 16;   // RNE bf16 in low 16
}

// ---------------------------------------------------------------------------
// prep: Asb[512][512] bf16 from As[500][500], zero-padded.
// ---------------------------------------------------------------------------
__global__ __launch_bounds__(256) void prep_k(const float* __restrict__ As,
                                              unsigned short* __restrict__ Asb) {
    int idx = blockIdx.x * 256 + threadIdx.x;   // 512*512 = 262144
    int s = idx >> 9, k = idx & 511;
    unsigned short v = 0;
    if (s < SS && k < SS) v = (unsigned short)f2bf(As[(size_t)s * SS + k]);
    Asb[idx] = v;
}

// ---------------------------------------------------------------------------
// lin1t: xf32[bt][s][f] = x@W1^T + b1 ; also writes xT[bt][f][k=s] bf16
// grid (8 s-tiles, 64 bt), block 256
// ---------------------------------------------------------------------------
__global__ __launch_bounds__(256) void lin1t_k(const float* __restrict__ x,
                                               const float* __restrict__ W1,
                                               const float* __restrict__ b1,
                                               float* __restrict__ xf32,
                                               unsigned short* __restrict__ xT) {
    __shared__ float Xs[64][33];
    __shared__ float Wl[FIN][FF];
    __shared__ float Ot[64][65];
    __shared__ float bl[FF];
    int tid = threadIdx.x;
    int bt = blockIdx.y, s0 = blockIdx.x * 64;

    for (int i = tid; i < FIN * FF; i += 256) { int f = i >> 5, j = i & 31; Wl[j][f] = W1[i]; }
    if (tid < FF) bl[tid] = b1[tid];
    const float* xb = x + (size_t)bt * SS * FIN;
    #pragma unroll
    for (int i = 0; i < 8; ++i) {
        int lin = i * 256 + tid; int r = lin >> 5, j = lin & 31;
        int s = s0 + r;
        Xs[r][j] = (s < SS) ? xb[(size_t)s * FIN + j] : 0.f;
    }
    __syncthreads();
    int f = tid & 63, sq = tid >> 6;
    for (int i = 0; i < 16; ++i) {
        int r = sq * 16 + i;
        float acc = bl[f];
        #pragma unroll
        for (int j = 0; j < FIN; ++j) acc += Xs[r][j] * Wl[j][f];
        Ot[r][f] = (s0 + r < SS) ? acc : 0.f;
    }
    __syncthreads();
    // natural fp32 write
    {
        int r = tid >> 2, c = (tid & 3) * 16;
        int s = s0 + r;
        if (s < SS) {
            float* dst = xf32 + ((size_t)bt * SS + s) * FF + c;
            #pragma unroll
            for (int q = 0; q < 4; ++q) {
                float4 t = make_float4(Ot[r][c+4*q], Ot[r][c+4*q+1], Ot[r][c+4*q+2], Ot[r][c+4*q+3]);
                *(float4*)(dst + 4*q) = t;
            }
        }
    }
    // transposed bf16 write (covers k-pad with zeros)
    {
        int ff = tid >> 2, sc = (tid & 3) * 16;
        unsigned short tmp[16];
        #pragma unroll
        for (int i = 0; i < 16; ++i) tmp[i] = (unsigned short)f2bf(Ot[sc + i][ff]);
        unsigned short* dst = xT + ((size_t)bt * FF + ff) * KP + s0 + sc;
        #pragma unroll
        for (int q = 0; q < 2; ++q) {
            int4 w;
            w.x = tmp[q*8+0] | (tmp[q*8+1] << 16); w.y = tmp[q*8+2] | (tmp[q*8+3] << 16);
            w.z = tmp[q*8+4] | (tmp[q*8+5] << 16); w.w = tmp[q*8+6] | (tmp[q*8+7] << 16);
            *(int4*)(dst + q * 8) = w;
        }
    }
}

// ---------------------------------------------------------------------------
// t2bf: src fp32 [bt][s][f] -> dst bf16 [bt][f][k=s] (zero-padded k)
// grid (8 s-tiles, 64 bt)
// ---------------------------------------------------------------------------
__global__ __launch_bounds__(256) void t2bf_k(const float* __restrict__ src,
                                              unsigned short* __restrict__ dst) {
    __shared__ float Ot[64][65];
    int tid = threadIdx.x;
    int bt = blockIdx.y, s0 = blockIdx.x * 64;
    const float* sb = src + (size_t)bt * SS * FF;
    #pragma unroll
    for (int i = 0; i < 16; ++i) {
        int lin = i * 256 + tid; int r = lin >> 6, f = lin & 63;
        int s = s0 + r;
        Ot[r][f] = (s < SS) ? sb[(size_t)s * FF + f] : 0.f;
    }
    __syncthreads();
    int ff = tid >> 2, sc = (tid & 3) * 16;
    unsigned short tmp[16];
    #pragma unroll
    for (int i = 0; i < 16; ++i) tmp[i] = (unsigned short)f2bf(Ot[sc + i][ff]);
    unsigned short* dp = dst + ((size_t)bt * FF + ff) * KP + s0 + sc;
    #pragma unroll
    for (int q = 0; q < 2; ++q) {
        int4 w;
        w.x = tmp[q*8+0] | (tmp[q*8+1] << 16); w.y = tmp[q*8+2] | (tmp[q*8+3] << 16);
        w.z = tmp[q*8+4] | (tmp[q*8+5] << 16); w.w = tmp[q*8+6] | (tmp[q*8+7] << 16);
        *(int4*)(dp + q * 8) = w;
    }
}

// ---------------------------------------------------------------------------
// spatial_mm (LDS-free MFMA): u32[bt][s][f] = sum_k As[s,k] v[k,f]
// A-frags from Asb[s][k] (k-contig), B-frags from vT[bt][f][k] (k-contig).
// grid (8 s-tiles, 64 bt), block 256 = 4 waves; wave tile 16s x 64f.
// ---------------------------------------------------------------------------
__global__ __launch_bounds__(256) void spatial_mm(const unsigned short* __restrict__ Asb,
                                                  const unsigned short* __restrict__ vT,
                                                  float* __restrict__ u) {
    int bt = blockIdx.y;
    int tid = threadIdx.x;
    int wave = tid >> 6, lane = tid & 63;
    int l16 = lane & 15, quad = lane >> 4;

    int srow = blockIdx.x * 64 + wave * 16 + l16;
    const unsigned short* ap = Asb + (size_t)srow * KP + quad * 8;
    const unsigned short* bp = vT + ((size_t)bt * FF + l16) * KP + quad * 8;

    floatx4 acc[4] = {};
    #pragma unroll 4
    for (int k0 = 0; k0 < KP; k0 += 32) {
        bf16x8 a = *(const bf16x8*)(ap + k0);
        #pragma unroll
        for (int nt = 0; nt < 4; ++nt) {
            bf16x8 b = *(const bf16x8*)(bp + (size_t)nt * 16 * KP + k0);
            acc[nt] = __builtin_amdgcn_mfma_f32_16x16x32_bf16(a, b, acc[nt], 0, 0, 0);
        }
    }

    // C/D: col(f)=l16, row(s)=quad*4+r
    int sbase = blockIdx.x * 64 + wave * 16 + quad * 4;
    float* ub = u + (size_t)bt * SS * FF;
    #pragma unroll
    for (int nt = 0; nt < 4; ++nt) {
        int f = nt * 16 + l16;
        #pragma unroll
        for (int r = 0; r < 4; ++r) {
            int s = sbase + r;
            if (s < SS) ub[(size_t)s * FF + f] = acc[nt][r];
        }
    }
}

// ---------------------------------------------------------------------------
// combine: y[b,t,s,f] = s0 v + s1 u + sum_{t'} At[t,t'] (s2 v[t'] + s3 u[t'])
// ---------------------------------------------------------------------------
__global__ __launch_bounds__(256) void combine_k(const float* __restrict__ v,
                                                 const float* __restrict__ u,
                                                 const float* __restrict__ At,
                                                 const float* __restrict__ sc,
                                                 float* __restrict__ y) {
    __shared__ float Atl[TT * TT];
    __shared__ float sl[4];
    int tid = threadIdx.x;
    if (tid < TT * TT) Atl[tid] = At[tid];
    if (tid < 4) sl[tid] = sc[tid];
    __syncthreads();

    int idx = blockIdx.x * 256 + tid;        // over B*S*F = 256000
    int f = idx & 63;
    int rest = idx >> 6;
    int si = rest % SS;
    int b  = rest / SS;
    size_t base = ((size_t)b * TT * SS + si) * FF + f;

    float vv[TT], uu[TT], ww[TT];
    #pragma unroll
    for (int t = 0; t < TT; ++t) {
        vv[t] = v[base + (size_t)t * TS_STRIDE];
        uu[t] = u[base + (size_t)t * TS_STRIDE];
    }
    float s0 = sl[0], s1 = sl[1], s2 = sl[2], s3 = sl[3];
    #pragma unroll
    for (int t = 0; t < TT; ++t) ww[t] = s2 * vv[t] + s3 * uu[t];
    #pragma unroll
    for (int t = 0; t < TT; ++t) {
        float r = s0 * vv[t] + s1 * uu[t];
        #pragma unroll
        for (int tp = 0; tp < TT; ++tp) r += Atl[t * TT + tp] * ww[tp];
        y[base + (size_t)t * TS_STRIDE] = r;
    }
}

// ---------------------------------------------------------------------------
// hcombine: out[row,f] = tanh( y0@H0 + y1@H1 + y2@H2 )
// ---------------------------------------------------------------------------
__global__ __launch_bounds__(256) void hcombine_k(const float* __restrict__ y0,
                                                  const float* __restrict__ y1,
                                                  const float* __restrict__ y2,
                                                  const float* __restrict__ H,
                                                  float* __restrict__ out) {
    __shared__ float Hl[3][FF][FF];   // 48 KB
    int tid = threadIdx.x;
    for (int i = tid; i < 3 * FF * FF; i += 256) ((float*)Hl)[i] = H[i];
    __syncthreads();

    int tx = tid & 15, ty = tid >> 4;
    int row = blockIdx.x * 16 + ty;
    const float* p0 = y0 + (size_t)row * FF;
    const float* p1 = y1 + (size_t)row * FF;
    const float* p2 = y2 + (size_t)row * FF;
    int f4 = tx * 4;

    float acc0 = 0.f, acc1 = 0.f, acc2 = 0.f, acc3 = 0.f;
    #pragma unroll 8
    for (int j = 0; j < FF; ++j) {
        float a0 = p0[j], a1 = p1[j], a2 = p2[j];
        float4 h0 = *(const float4*)&Hl[0][j][f4];
        float4 h1 = *(const float4*)&Hl[1][j][f4];
        float4 h2 = *(const float4*)&Hl[2][j][f4];
        acc0 += a0 * h0.x + a1 * h1.x + a2 * h2.x;
        acc1 += a0 * h0.y + a1 * h1.y + a2 * h2.y;
        acc2 += a0 * h0.z + a1 * h1.z + a2 * h2.z;
        acc3 += a0 * h0.w + a1 * h1.w + a2 * h2.w;
    }
    float4 r;
    r.x = tanhf(acc0); r.y = tanhf(acc1); r.z = tanhf(acc2); r.w = tanhf(acc3);
    *(float4*)(out + (size_t)row * FF + f4) = r;
}

// ---------------------------------------------------------------------------
// zredlin2: out[b,s,f] = b2[f]*sum(m) + sum_j (sum_t m[t] xf[b,t,s,j]) * W2[f,j]
// grid (32 s-tiles of 16, 8 b)
// ---------------------------------------------------------------------------
__global__ __launch_bounds__(256) void zredlin2_k(const float* __restrict__ xf,
                                                  const float* __restrict__ W2,
                                                  const float* __restrict__ b2,
                                                  const float* __restrict__ merge,
                                                  float* __restrict__ out) {
    __shared__ float Wl[FF][FF + 1];
    __shared__ float zt[16][FF + 1];
    __shared__ float ml[TT];
    int tid = threadIdx.x;
    int b = blockIdx.y, s0 = blockIdx.x * 16;

    for (int i = tid; i < FF * FF; i += 256) { int f = i >> 6, j = i & 63; Wl[j][f] = W2[i]; }
    if (tid < TT) ml[tid] = merge[tid];
    __syncthreads();

    float m[TT];
    #pragma unroll
    for (int t = 0; t < TT; ++t) m[t] = ml[t];
    float msum = 0.f;
    #pragma unroll
    for (int t = 0; t < TT; ++t) msum += m[t];

    // phase 1: z tile [16 s][64 f]
    #pragma unroll
    for (int p = 0; p < 4; ++p) {
        int lin = p * 256 + tid;
        int sl = lin >> 6, f = lin & 63;
        int s = s0 + sl;
        float acc = 0.f;
        if (s < SS) {
            #pragma unroll
            for (int t = 0; t < TT; ++t)
                acc += m[t] * xf[((size_t)(b * TT + t) * SS + s) * FF + f];
        }
        zt[sl][f] = acc;
    }
    __syncthreads();

    // phase 2: out rows
    int f = tid & 63, sq = tid >> 6;
    #pragma unroll
    for (int i = 0; i < 4; ++i) {
        int sl = sq * 4 + i;
        int s = s0 + sl;
        if (s < SS) {
            float acc = b2[f] * msum;
            #pragma unroll
            for (int j = 0; j < FF; ++j) acc += zt[sl][j] * Wl[j][f];
            out[((size_t)b * SS + s) * FF + f] = acc;
        }
    }
}

// ---------------------------------------------------------------------------
extern "C" void kernel_launch(void* const* d_in, const int* in_sizes, int n_in,
                              void* d_out, int out_size, void* d_ws, size_t ws_size,
                              hipStream_t stream) {
    const float* x     = (const float*)d_in[0];
    const float* At    = (const float*)d_in[1];
    const float* As    = (const float*)d_in[2];
    const float* sc    = (const float*)d_in[3];
    const float* H     = (const float*)d_in[4];
    const float* W1    = (const float*)d_in[5];
    const float* b1    = (const float*)d_in[6];
    const float* W2    = (const float*)d_in[7];
    const float* b2    = (const float*)d_in[8];
    const float* merge = (const float*)d_in[9];
    float* out = (float*)d_out;

    char* ws = (char*)d_ws;
    unsigned short* Asb  = (unsigned short*)(ws);                 // 512*512*2 = 524288
    unsigned short* curT = (unsigned short*)(ws + 524288);        // 4 MB
    unsigned short* y1T  = (unsigned short*)(ws + 4718592);       // 4 MB
    float* xfA32 = (float*)(ws + 8912896);                        // 8.192 MB
    float* xfB32 = (float*)(ws + 17104896);
    float* u32   = (float*)(ws + 25296896);
    float* y132  = (float*)(ws + 33488896);
    float* y232  = (float*)(ws + 41680896);

    prep_k<<<1024, 256, 0, stream>>>(As, Asb);
    lin1t_k<<<dim3(8, BB * TT), 256, 0, stream>>>(x, W1, b1, xfA32, curT);

    float* cur = xfA32;
    float* nxt = xfB32;
    for (int l = 0; l < 3; ++l) {
        spatial_mm<<<dim3(8, BB * TT), 256, 0, stream>>>(Asb, curT, u32);
        combine_k<<<1000, 256, 0, stream>>>(cur, u32, At, sc, y132);
        t2bf_k<<<dim3(8, BB * TT), 256, 0, stream>>>(y132, y1T);
        spatial_mm<<<dim3(8, BB * TT), 256, 0, stream>>>(Asb, y1T, u32);
        combine_k<<<1000, 256, 0, stream>>>(y132, u32, At, sc, y232);
        hcombine_k<<<NROWS / 16, 256, 0, stream>>>(cur, y132, y232,
                                                   H + (size_t)l * 3 * FF * FF, nxt);
        if (l < 2)
            t2bf_k<<<dim3(8, BB * TT), 256, 0, stream>>>(nxt, curT);
        float* tmp = cur; cur = nxt; nxt = tmp;
    }
    zredlin2_k<<<dim3(32, 8), 256, 0, stream>>>(cur, W2, b2, merge, out);
}